// Round 4
// baseline (556.438 us; speedup 1.0000x reference)
//
#include <hip/hip_runtime.h>
#include <hip/hip_cooperative_groups.h>
#include <math.h>

namespace cg = cooperative_groups;

// ---------------- problem constants (static shapes) ----------------
#define NIMG 8
#define ATOT 65472
#define KTOT 6960          // 2000+2000+2000+768+192
#define POST 2000
#define TILES_PER_IMG 1668 // 528*3 + 78 + 6
#define NTILES (NIMG*TILES_PER_IMG)
#define ESEG 1024          // edges per (task,gi) segment cap
// Exact tie boundary: f32_div(inter,uni) > 0.7f  <=>  inter/uni >= M_TIE.
// M_TIE = midpoint(0.7f, nextafterf(0.7f)) = 23488103/2^25 (25-bit mantissa;
// ties-to-even rounds the midpoint UP to the even mantissa 0x3F333334 > 0.7f).
// (double)inter >= M_TIE*(double)uni is exact: 25b x 24b = 49b <= 53b.
#define M_TIE 0.7000000178813934326171875

__constant__ int c_NAPL[5]  = {49152,12288,3072,768,192};
__constant__ int c_LOFF[5]  = {0,49152,61440,64512,65280};
__constant__ int c_KSEL[5]  = {2000,2000,2000,768,192};
__constant__ int c_CBASE[5] = {0,2000,4000,6000,6768};
__constant__ int c_GLVL[5]  = {32,32,32,12,3};      // ceil(k/64)
__constant__ int c_TILEPFX[6] = {0,528,1056,1584,1662,1668};
__constant__ int c_SORTM[5] = {2048,2048,2048,1024,256};
// slice tables: 13 append-slots per image (first 11 are also hist-slots, lvl<3)
__constant__ int c_SLVL[13]  = {0,0,0,0,0,0,0,0,1,1,2,3,4};
__constant__ int c_SOFF13[13]= {0,6144,12288,18432,24576,30720,36864,43008,0,6144,0,0,0};
__constant__ int c_SLEN[13]  = {6144,6144,6144,6144,6144,6144,6144,6144,6144,6144,3072,768,192};
__constant__ int c_HS0[3] = {0,8,10};   // first hist-slot per lvl
__constant__ int c_HSN[3] = {8,2,1};    // hist-slots per lvl

// monotone float->uint map (order-preserving for all finite floats)
__device__ __forceinline__ unsigned f2u(float f){
  unsigned b = __float_as_uint(f);
  return (b & 0x80000000u) ? ~b : (b | 0x80000000u);
}
// composite key: (value desc, global idx asc) when sorted descending
__device__ __forceinline__ unsigned long long mkkey(unsigned u, unsigned gidx){
  return ((unsigned long long)u << 32) | (unsigned long long)(0xFFFFFFFFu - gidx);
}

// in-LDS bitonic sort, descending, m = power of two (uniform per block)
__device__ void bitonic_desc(unsigned long long* sb, int m){
  int tid = threadIdx.x, nthr = blockDim.x;
  for (int size = 2; size <= m; size <<= 1){
    for (int stride = size >> 1; stride > 0; stride >>= 1){
      __syncthreads();
      for (int t = tid; t < (m >> 1); t += nthr){
        int lo = t & (stride - 1);
        int i  = ((t - lo) << 1) + lo;
        int j  = i + stride;
        bool desc = ((i & size) == 0);
        unsigned long long a = sb[i], b = sb[j];
        if (desc ? (a < b) : (a > b)) { sb[i] = b; sb[j] = a; }
      }
    }
  }
  __syncthreads();
}

__device__ __forceinline__ int cntGreater(const unsigned long long* base, int len,
                                          unsigned long long x){
  int lo = 0, hi = len;          // descending array, unique keys
  while (lo < hi){
    int mid = (lo + hi) >> 1;
    if (base[mid] > x) lo = mid + 1; else hi = mid;
  }
  return lo;
}

// ---------------- the whole pipeline in one cooperative kernel ----------------
__global__ void __launch_bounds__(256)
mega(const float* __restrict__ prop, const float* __restrict__ obj,
     char* __restrict__ ws, float* __restrict__ out, int out_n){
  cg::grid_group grid = cg::this_grid();
  __shared__ unsigned long long s_mem[7040];     // 56.3 KB, reused per phase
  __shared__ unsigned long long keepW[32], suppW[32], initW[32];
  __shared__ unsigned soff[33], wpfx[33];
  __shared__ int loff6[6], lcnt5[5];
  __shared__ unsigned s_u0, s_u1;
  __shared__ int s_changed;

  unsigned* cntA = (unsigned*)(ws);                              // 40
  unsigned* ecnt = (unsigned*)(ws + 160);                        // 40*32
  unsigned* T20  = (unsigned*)(ws + 5280);                       // 40
  unsigned* ccnt = (unsigned*)(ws + 5440);                       // 40 (zone ends 5600)
  unsigned long long* buf  = (unsigned long long*)(ws + 6144);   // 40*2048
  unsigned long long* cand = (unsigned long long*)(ws + 661504); // 8*6960
  unsigned long long* clist= (unsigned long long*)(ws + 1106944);
  float4*             cbox = (float4*)(ws + 1552384);            // 8*6960
  unsigned*           hist = (unsigned*)(ws + 2443264);          // 88*4096
  unsigned*           eseg = (unsigned*)(ws + 3885056);          // 40*32*1024

  int bid = blockIdx.x, tid = threadIdx.x;

  //======== Phase A: zero counters + d_out  |  per-slice 12-bit histograms ========
  if (bid < 88){
    unsigned* h = (unsigned*)s_mem;
    for (int i = tid; i < 4096; i += 256) h[i] = 0u;
    __syncthreads();
    int img = bid / 11, slot = bid % 11;
    int lvl = c_SLVL[slot], len = c_SLEN[slot];
    const float* o = obj + (size_t)img*ATOT + c_LOFF[lvl] + c_SOFF13[slot];
    for (int i = tid; i < len; i += 256) atomicAdd(&h[f2u(o[i]) >> 20], 1u);
    __syncthreads();
    unsigned* hout = hist + (size_t)bid*4096;
    for (int i = tid; i < 4096; i += 256) hout[i] = h[i];
  } else {
    int gt = (bid - 88)*256 + tid, gs = 168*256;
    unsigned* zw = (unsigned*)ws;
    for (int i = gt; i < 1400; i += gs) zw[i] = 0u;     // cntA+ecnt+T20+ccnt zone
    for (int i = gt; i < out_n; i += gs) out[i] = 0.f;  // zero-padded output
  }
  grid.sync();

  //======== Phase B: 12-bit threshold + 20-bit refinement (lvl<3) ========
  if (bid < 24){
    unsigned* csum = (unsigned*)s_mem;
    unsigned* h8   = ((unsigned*)s_mem) + 256;
    int img = bid / 3, lvl = bid % 3, task = img*5 + lvl;
    int hs0 = c_HS0[lvl], hsn = c_HSN[lvl];
    unsigned k = (unsigned)c_KSEL[lvl];
    unsigned s = 0;
    for (int hs = 0; hs < hsn; ++hs){
      const unsigned* h = hist + (size_t)(img*11 + hs0 + hs)*4096;
      for (int j = 0; j < 16; ++j) s += h[tid*16 + j];
    }
    csum[tid] = s;
    h8[tid] = 0u;
    __syncthreads();
    if (tid == 0){
      unsigned cum = 0, b12 = 0;     // cum accumulates count strictly above boundary
      for (int c = 255; c >= 0; --c){
        if (cum + csum[c] >= k){
          for (int j = 15; j >= 0; --j){
            unsigned bv = 0;
            for (int hs = 0; hs < hsn; ++hs)
              bv += hist[(size_t)(img*11 + hs0 + hs)*4096 + c*16 + j];
            if (cum + bv >= k){ b12 = (unsigned)(c*16 + j); break; }
            cum += bv;
          }
          break;
        }
        cum += csum[c];
      }
      s_u0 = b12; s_u1 = cum;
    }
    __syncthreads();
    unsigned b12 = s_u0, cntAb = s_u1;
    const float* o = obj + (size_t)img*ATOT + c_LOFF[lvl];
    int n = c_NAPL[lvl];
    for (int i = tid; i < n; i += 256){
      unsigned u = f2u(o[i]);
      if ((u >> 20) == b12) atomicAdd(&h8[(u >> 12) & 255u], 1u);
    }
    __syncthreads();
    if (tid == 0){
      unsigned cum = cntAb, t20 = (b12 << 8);
      for (int b = 255; b >= 0; --b){
        cum += h8[b];
        if (cum >= k){ t20 = (b12 << 8) | (unsigned)b; break; }
      }
      T20[task] = t20;   // overshoot past k now ~2-3 instead of ~500 -> cnt <= 2048
    }
  }
  grid.sync();

  //======== Phase C: append candidates with (u>>12) >= T20, 1 global atomic/block ========
  if (bid < 104){
    unsigned long long* lbuf = s_mem;   // 2048 keys
    int img = bid / 13, slot = bid % 13;
    int lvl = c_SLVL[slot], len = c_SLEN[slot], task = img*5 + lvl;
    unsigned T = T20[task];             // 0 for lvl>=3 -> append all
    if (tid == 0) s_u0 = 0u;
    __syncthreads();
    int abase = c_LOFF[lvl] + c_SOFF13[slot];
    const float* o = obj + (size_t)img*ATOT;
    for (int i = tid; i < len; i += 256){
      int a = abase + i;
      unsigned u = f2u(o[a]);
      if ((u >> 12) >= T){
        unsigned p = atomicAdd(&s_u0, 1u);      // LDS atomic
        if (p < 2048u) lbuf[p] = mkkey(u, (unsigned)a);
      }
    }
    __syncthreads();
    unsigned c = min(s_u0, 2048u);
    if (tid == 0) s_u1 = atomicAdd(&cntA[task], c);
    __syncthreads();
    unsigned gb = s_u1;
    unsigned long long* bp = buf + (size_t)task*2048;
    for (unsigned i = tid; i < c; i += 256){
      unsigned p = gb + i;
      if (p < 2048u) bp[p] = lbuf[i];
    }
  }
  grid.sync();

  //======== Phase D: per-task bitonic sort (m<=2048) + cand/cbox emission ========
  if (bid < 40){
    unsigned long long* sb = s_mem;
    int task = bid, img = task/5, lvl = task%5;
    int k = c_KSEL[lvl], m = c_SORTM[lvl];
    int cnt = (int)min(cntA[task], 2048u);      // superset of top-k by construction
    const unsigned long long* bp = buf + (size_t)task*2048;
    for (int i = tid; i < cnt; i += 256) sb[i] = bp[i];
    for (int i = cnt + tid; i < m; i += 256) sb[i] = 0ull;
    bitonic_desc(sb, m);
    const float4* pr = (const float4*)(prop + (size_t)img*ATOT*4);
    for (int i = tid; i < k; i += 256){
      unsigned long long key = sb[i];
      size_t slot = (size_t)img*KTOT + c_CBASE[lvl] + i;
      cand[slot] = key;
      unsigned gidx = 0xFFFFFFFFu - (unsigned)(key & 0xFFFFFFFFull);
      float4 p = pr[gidx];
      cbox[slot] = make_float4(fminf(fmaxf(p.x,0.f),512.f), fminf(fmaxf(p.y,0.f),512.f),
                               fminf(fmaxf(p.z,0.f),512.f), fminf(fmaxf(p.w,0.f),512.f));
    }
  }
  grid.sync();

  //======== Phase E: IoU tiles -> segmented edge lists (branchless, no division) ========
  {
    float4* colb = (float4*)s_mem;                        // 64 boxes
    float*  colA = (float*)(((char*)s_mem) + 1024);       // 64 areas
    for (int tile = bid; tile < NTILES; tile += 256){
      int img = tile / TILES_PER_IMG, r = tile % TILES_PER_IMG;
      int lvl = 0;
      while (r >= c_TILEPFX[lvl + 1]) ++lvl;
      int t = r - c_TILEPFX[lvl];
      int G = c_GLVL[lvl], k = c_KSEL[lvl];
      int gi = 0;
      while (t >= G - gi){ t -= G - gi; ++gi; }
      int gj = gi + t;
      int task = img*5 + lvl;
      const float4* cb = cbox + (size_t)img*KTOT + c_CBASE[lvl];
      __syncthreads();                       // LDS reuse fence from previous tile
      if (tid < 64){
        int jj = gj*64 + tid;
        float4 b = (jj < k) ? cb[jj] : make_float4(0.f,0.f,0.f,0.f);
        colb[tid] = b;
        colA[tid] = (b.z - b.x) * (b.w - b.y);
      }
      __syncthreads();
      int row = tid & 63, chunk = tid >> 6;  // 4 waves x (64 rows x 16 cols)
      int i = gi*64 + row;
      float4 a = (i < k) ? cb[i] : make_float4(0.f,0.f,0.f,0.f);
      float aarea = (a.z - a.x) * (a.w - a.y);
      unsigned word = 0u;
      int jbase = chunk*16;
      for (int jj = 0; jj < 16; ++jj){
        float4 b = colb[jbase + jj];         // wave-uniform address: LDS broadcast
        float barea = colA[jbase + jj];
        float ix = fminf(a.z, b.z) - fmaxf(a.x, b.x);
        float iy = fminf(a.w, b.w) - fmaxf(a.y, b.y);
        float inter = ix * iy;
        float uni = (aarea + barea) - inter;
        bool hit = (ix > 0.f) & (iy > 0.f) & ((double)inter >= M_TIE * (double)uni);
        word |= hit ? (1u << jj) : 0u;
      }
      if (gi == gj){                         // keep strictly upper triangle j>i
        int lo = row - jbase + 1;
        unsigned dm = (lo <= 0) ? 0xFFFFu : ((lo >= 16) ? 0u : (0xFFFFu << lo));
        word &= dm;
      }
      int lane = tid & 63;
      int nb = __popc(word);
      int pfx = nb;
      for (int d = 1; d < 64; d <<= 1){
        int v = __shfl_up(pfx, d);
        if (lane >= d) pfx += v;
      }
      int total = __shfl(pfx, 63);
      if (total > 0){
        unsigned base = 0;
        if (lane == 0) base = atomicAdd(&ecnt[task*32 + gi], (unsigned)total);
        base = __shfl(base, 0);
        unsigned idx = base + (unsigned)(pfx - nb);
        unsigned* ep = eseg + (size_t)(task*32 + gi)*ESEG;
        unsigned w = word;
        while (w){
          int jj = __ffs(w) - 1; w &= w - 1;
          if (idx < ESEG) ep[idx] = ((unsigned)i << 16) | (unsigned)(gj*64 + jbase + jj);
          ++idx;
        }
      }
    }
  }
  grid.sync();

  //======== Phase F: greedy-NMS fixpoint on LDS edges + ordered compaction ========
  if (bid < 40){
    unsigned* ledge = (unsigned*)s_mem;   // 6144-edge cache
    int task = bid, img = task/5, lvl = task%5;
    int k = c_KSEL[lvl], nW = c_GLVL[lvl];
    if (tid == 0){
      unsigned s = 0;
      for (int w = 0; w < nW; ++w){ soff[w] = s; s += min(ecnt[task*32 + w], (unsigned)ESEG); }
      soff[nW] = s;
    }
    if (tid < 32){
      unsigned long long v = 0ull;
      if (tid < nW){
        int rem = k - tid*64;
        v = (rem >= 64) ? ~0ull : ((1ull << rem) - 1ull);
      }
      initW[tid] = v; keepW[tid] = v;
    }
    __syncthreads();
    for (int w = 0; w < nW; ++w){
      unsigned c = soff[w+1] - soff[w];
      const unsigned* ep = eseg + (size_t)(task*32 + w)*ESEG;
      for (unsigned e = tid; e < c; e += 256){
        unsigned p = soff[w] + e;
        if (p < 6144u) ledge[p] = ep[e];
      }
    }
    __syncthreads();
    // greedy NMS == unique kernel of the suppression DAG (edges i<j only);
    // Jacobi iteration to fixpoint, deterministic OR-reduction.
    for (int iter = 0; iter < 4096; ++iter){
      if (tid < 32) suppW[tid] = 0ull;
      if (tid == 0) s_changed = 0;
      __syncthreads();
      for (int w = 0; w < nW; ++w){
        unsigned c = soff[w+1] - soff[w];
        const unsigned* ep = eseg + (size_t)(task*32 + w)*ESEG;
        for (unsigned e = tid; e < c; e += 256){
          unsigned p = soff[w] + e;
          unsigned ed = (p < 6144u) ? ledge[p] : ep[e];
          int i = (int)(ed >> 16), j = (int)(ed & 0xFFFFu);
          if ((keepW[i >> 6] >> (i & 63)) & 1ull)
            atomicOr(&suppW[j >> 6], 1ull << (j & 63));
        }
      }
      __syncthreads();
      if (tid < 32){
        unsigned long long nk = initW[tid] & ~suppW[tid];
        if (nk != keepW[tid]){ keepW[tid] = nk; s_changed = 1; }
      }
      __syncthreads();
      if (!s_changed) break;
    }
    if (tid == 0){
      unsigned s = 0;
      for (int w = 0; w < nW; ++w){ wpfx[w] = s; s += (unsigned)__popcll(keepW[w]); }
      ccnt[task] = s;
    }
    __syncthreads();
    size_t base = (size_t)img*KTOT + c_CBASE[lvl];
    for (int i = tid; i < k; i += 256){
      unsigned long long w = keepW[i >> 6];
      if ((w >> (i & 63)) & 1ull){
        unsigned long long lowmask = (i & 63) ? ((1ull << (i & 63)) - 1ull) : 0ull;
        unsigned rank = wpfx[i >> 6] + (unsigned)__popcll(w & lowmask);
        clist[base + rank] = cand[base + i];
      }
    }
  }
  grid.sync();

  //======== Phase G: 5-way rank merge (no sort) + output ========
  if (bid < 16){
    unsigned long long* keys = s_mem;   // up to 6960 keys (55.7 KB)
    int img = bid >> 1, half = bid & 1;
    if (tid == 0){
      int s = 0;
      for (int l = 0; l < 5; ++l){ lcnt5[l] = (int)ccnt[img*5 + l]; loff6[l] = s; s += lcnt5[l]; }
      loff6[5] = s;
    }
    __syncthreads();
    for (int l = 0; l < 5; ++l){
      size_t gb = (size_t)img*KTOT + c_CBASE[l];
      int c = lcnt5[l], lo = loff6[l];
      for (int e = tid; e < c; e += 256) keys[lo + e] = clist[gb + e];
    }
    __syncthreads();
    const float4* pr = (const float4*)(prop + (size_t)img*ATOT*4);
    const float*  o  = obj + (size_t)img*ATOT;
    float* ob = out + (size_t)img*POST*4;
    float* os = out + (size_t)NIMG*POST*4 + (size_t)img*POST;
    int tot = loff6[5];
    for (int tt = tid; ; tt += 256){
      int t = 2*tt + half;
      if (t >= tot) break;
      int lvl = 0;
      while (t >= loff6[lvl + 1]) ++lvl;
      unsigned long long x = keys[t];
      int pos = t - loff6[lvl];
      for (int l = 0; l < 5; ++l){
        if (l == lvl) continue;
        pos += cntGreater(keys + loff6[l], lcnt5[l], x);
      }
      if (pos < POST){
        unsigned gidx = 0xFFFFFFFFu - (unsigned)(x & 0xFFFFFFFFull);
        float4 p = pr[gidx];
        ob[pos*4 + 0] = fminf(fmaxf(p.x, 0.f), 512.f);
        ob[pos*4 + 1] = fminf(fmaxf(p.y, 0.f), 512.f);
        ob[pos*4 + 2] = fminf(fmaxf(p.z, 0.f), 512.f);
        ob[pos*4 + 3] = fminf(fmaxf(p.w, 0.f), 512.f);
        double sgm = 1.0 / (1.0 + exp(-(double)o[gidx]));  // correctly-rounded f32 sigmoid
        os[pos] = (float)sgm;
      }
    }
  }
}

// ---------------- launch ----------------
extern "C" void kernel_launch(void* const* d_in, const int* in_sizes, int n_in,
                              void* d_out, int out_size, void* d_ws, size_t ws_size,
                              hipStream_t stream){
  const float* prop = (const float*)d_in[0];
  const float* obj  = (const float*)d_in[1];
  char* ws = (char*)d_ws;
  float* out = (float*)d_out;
  int out_n = out_size;
  void* args[] = {(void*)&prop, (void*)&obj, (void*)&ws, (void*)&out, (void*)&out_n};
  // one cooperative launch; 256 blocks (1/CU guaranteed co-resident), 6 grid syncs
  hipLaunchCooperativeKernel((void*)mega, dim3(256), dim3(256), args, 0, stream);
}

// Round 5
// 244.376 us; speedup vs baseline: 2.2770x; 2.2770x over previous
//
#include <hip/hip_runtime.h>
#include <math.h>

// ---------------- problem constants (static shapes) ----------------
#define NIMG 8
#define ATOT 65472
#define KTOT 6960          // 2000+2000+2000+768+192
#define POST 2000
#define TILES_PER_IMG 1668 // 528*3 + 78 + 6
#define NTILES (NIMG*TILES_PER_IMG)
#define ESEG 1024          // edges per (task,gi) segment cap
// Exact tie boundary: f32_div(inter,uni) > 0.7f  <=>  inter/uni >= M_TIE.
// M_TIE = midpoint(0.7f, nextafterf(0.7f)); 25-bit mantissa; ties-to-even sends
// the midpoint UP. (double)inter >= M_TIE*(double)uni is exact: 25b+24b <= 53b.
// Validated bit-exact vs division predicate in round 4 (absmax 0.0).
#define M_TIE 0.7000000178813934326171875

__constant__ int c_NAPL[5]  = {49152,12288,3072,768,192};
__constant__ int c_LOFF[5]  = {0,49152,61440,64512,65280};
__constant__ int c_KSEL[5]  = {2000,2000,2000,768,192};
__constant__ int c_CBASE[5] = {0,2000,4000,6000,6768};
__constant__ int c_GLVL[5]  = {32,32,32,12,3};      // ceil(k/64)
__constant__ int c_TILEPFX[6] = {0,528,1056,1584,1662,1668};
// slice tables: 13 append-slots per image (first 11 are also hist-slots, lvl<3)
__constant__ int c_SLVL[13]  = {0,0,0,0,0,0,0,0,1,1,2,3,4};
__constant__ int c_SOFF13[13]= {0,6144,12288,18432,24576,30720,36864,43008,0,6144,0,0,0};
__constant__ int c_SLEN[13]  = {6144,6144,6144,6144,6144,6144,6144,6144,6144,6144,3072,768,192};
__constant__ int c_HS0[5] = {0,8,10,0,0};   // first hist-slot per lvl (lvl<3)
__constant__ int c_HSN[5] = {8,2,1,0,0};    // hist-slots per lvl

// monotone float->uint map (order-preserving for all finite floats)
__device__ __forceinline__ unsigned f2u(float f){
  unsigned b = __float_as_uint(f);
  return (b & 0x80000000u) ? ~b : (b | 0x80000000u);
}
// composite key: (value desc, global idx asc) when sorted descending
__device__ __forceinline__ unsigned long long mkkey(unsigned u, unsigned gidx){
  return ((unsigned long long)u << 32) | (unsigned long long)(0xFFFFFFFFu - gidx);
}

// in-LDS bitonic sort, descending, m = power of two (uniform per block)
__device__ void bitonic_desc(unsigned long long* sb, int m){
  int tid = threadIdx.x, nthr = blockDim.x;
  for (int size = 2; size <= m; size <<= 1){
    for (int stride = size >> 1; stride > 0; stride >>= 1){
      __syncthreads();
      for (int t = tid; t < (m >> 1); t += nthr){
        int lo = t & (stride - 1);
        int i  = ((t - lo) << 1) + lo;
        int j  = i + stride;
        bool desc = ((i & size) == 0);
        unsigned long long a = sb[i], b = sb[j];
        if (desc ? (a < b) : (a > b)) { sb[i] = b; sb[j] = a; }
      }
    }
  }
  __syncthreads();
}

// ---------------- K1: per-block LDS 12-bit histogram + counter zeroing ----------------
extern "C" __global__ void __launch_bounds__(256)
k_hist(const float* __restrict__ obj, unsigned* __restrict__ hist,
       unsigned* __restrict__ zzone){   // zzone = cntA(40) + ecnt(1280), contiguous
  __shared__ unsigned h[4096];
  int bid = blockIdx.x, tid = threadIdx.x;
  if (bid == 88){
    for (int i = tid; i < 1320; i += 256) zzone[i] = 0u;
    return;
  }
  int img = bid / 11, slot = bid % 11;
  int lvl = c_SLVL[slot], len = c_SLEN[slot];
  for (int i = tid; i < 4096; i += 256) h[i] = 0u;
  __syncthreads();
  const float* o = obj + (size_t)img*ATOT + c_LOFF[lvl] + c_SOFF13[slot];
  for (int i = tid; i < len; i += 256) atomicAdd(&h[f2u(o[i]) >> 20], 1u);
  __syncthreads();
  unsigned* hout = hist + (size_t)bid*4096;
  for (int i = tid; i < 4096; i += 256) hout[i] = h[i];
}

// ---------------- K2: inline threshold + slice append, 1 global atomic per block ----------------
extern "C" __global__ void __launch_bounds__(256)
k_append(const float* __restrict__ obj, const unsigned* __restrict__ hist,
         unsigned* __restrict__ cntA, unsigned long long* __restrict__ buf){
  __shared__ unsigned hcomb[4096];          // 16 KB combined histogram
  __shared__ unsigned csum[256];
  __shared__ unsigned long long lbuf[2048]; // 16 KB append buffer
  __shared__ unsigned s_T, s_cnt, s_gbase;
  int bid = blockIdx.x, tid = threadIdx.x;
  int img = bid / 13, slot = bid % 13;
  int lvl = c_SLVL[slot], len = c_SLEN[slot], task = img*5 + lvl;

  if (lvl < 3){
    // rebuild this task's combined 4096-bin histogram; find k-th-largest's bin b12
    int hs0 = c_HS0[lvl], hsn = c_HSN[lvl];
    unsigned s = 0;
    for (int b = 0; b < 16; ++b){
      unsigned v = 0;
      for (int hs = 0; hs < hsn; ++hs)
        v += hist[(size_t)(img*11 + hs0 + hs)*4096 + tid*16 + b];
      hcomb[tid*16 + b] = v;
      s += v;
    }
    csum[tid] = s;
    __syncthreads();
    if (tid == 0){
      unsigned k = (unsigned)c_KSEL[lvl], cum = 0, bstar = 0;
      for (int c = 255; c >= 0; --c){
        if (cum + csum[c] >= k){
          for (int j = 15; j >= 0; --j){
            cum += hcomb[c*16 + j];
            if (cum >= k){ bstar = (unsigned)(c*16 + j); break; }
          }
          break;
        }
        cum += csum[c];
      }
      s_T = bstar;
    }
  } else if (tid == 0) s_T = 0u;
  if (tid == 0) s_cnt = 0u;
  __syncthreads();
  unsigned T = s_T;

  int abase = c_LOFF[lvl] + c_SOFF13[slot];
  const float* o = obj + (size_t)img*ATOT;
  for (int i = tid; i < len; i += 256){
    int a = abase + i;
    unsigned u = f2u(o[a]);
    if ((u >> 20) >= T){
      unsigned p = atomicAdd(&s_cnt, 1u);   // LDS atomic
      if (p < 2048u) lbuf[p] = mkkey(u, (unsigned)a);
    }
  }
  __syncthreads();
  unsigned c = min(s_cnt, 2048u);
  if (tid == 0) s_gbase = atomicAdd(&cntA[task], c);  // one global atomic per block
  __syncthreads();
  unsigned gb = s_gbase;
  unsigned long long* bp = buf + (size_t)task*4096;
  for (unsigned i = tid; i < c; i += 256){
    unsigned p = gb + i;
    if (p < 4096u) bp[p] = lbuf[i];
  }
}

// ---------------- K3: per-task sort (<=4096) + emit sorted cand + clipped boxes ----------------
extern "C" __global__ void __launch_bounds__(1024)
k_sort(const float* __restrict__ prop, const unsigned* __restrict__ cntA,
       const unsigned long long* __restrict__ buf,
       unsigned long long* __restrict__ cand, float4* __restrict__ cbox){
  __shared__ unsigned long long sb[4096];   // 32 KB
  int task = blockIdx.x, img = task / 5, lvl = task % 5;
  int k = c_KSEL[lvl], tid = threadIdx.x;
  int cnt = (int)min(cntA[task], 4096u);    // superset of top-k by construction
  const unsigned long long* b = buf + (size_t)task*4096;
  for (int i = tid; i < cnt; i += 1024) sb[i] = b[i];
  int m = 256; while (m < k || m < cnt) m <<= 1;
  for (int i = cnt + tid; i < m; i += 1024) sb[i] = 0ull;
  bitonic_desc(sb, m);

  const float4* pr = (const float4*)(prop + (size_t)img*ATOT*4);
  for (int i = tid; i < k; i += 1024){
    unsigned long long key = sb[i];
    size_t slot = (size_t)img*KTOT + c_CBASE[lvl] + i;
    cand[slot] = key;
    unsigned gidx = 0xFFFFFFFFu - (unsigned)(key & 0xFFFFFFFFull);
    float4 p = pr[gidx];
    cbox[slot] = make_float4(fminf(fmaxf(p.x,0.f),512.f), fminf(fmaxf(p.y,0.f),512.f),
                             fminf(fmaxf(p.z,0.f),512.f), fminf(fmaxf(p.w,0.f),512.f));
  }
}

// ---------------- K4: branchless IoU tiles -> segmented edge lists; zero d_out ----------------
extern "C" __global__ void __launch_bounds__(64)
k_mask(const float4* __restrict__ cbox, unsigned* __restrict__ ecnt,
       unsigned* __restrict__ eseg, float4* __restrict__ out4, int out_n4){
  __shared__ float4 colb[64];
  __shared__ float  colA[64];
  int bid = blockIdx.x, lane = threadIdx.x;
  // fold d_out zero-fill into this (pre-merge) kernel: first 313 blocks
  if (bid < 313){
    int i = bid*64 + lane;
    if (i < out_n4) out4[i] = make_float4(0.f,0.f,0.f,0.f);
  }
  int img = bid / TILES_PER_IMG, r = bid % TILES_PER_IMG;
  int lvl = 0;
  while (r >= c_TILEPFX[lvl + 1]) ++lvl;
  int t = r - c_TILEPFX[lvl];
  int G = c_GLVL[lvl], k = c_KSEL[lvl];
  int gi = 0;
  while (t >= G - gi){ t -= G - gi; ++gi; }
  int gj = gi + t;
  int task = img*5 + lvl;
  const float4* cb = cbox + (size_t)img*KTOT + c_CBASE[lvl];

  int jj = gj*64 + lane;
  float4 bb = (jj < k) ? cb[jj] : make_float4(0.f,0.f,0.f,0.f);  // zero box never hits
  colb[lane] = bb;
  colA[lane] = (bb.z - bb.x) * (bb.w - bb.y);
  __syncthreads();

  int i = gi*64 + lane;
  unsigned long long word = 0ull;
  if (i < k){
    float4 a = cb[i];
    float aarea = (a.z - a.x) * (a.w - a.y);
    for (int j = 0; j < 64; ++j){
      float4 b = colb[j];                  // wave-uniform address: LDS broadcast
      float ix = fminf(a.z, b.z) - fmaxf(a.x, b.x);
      float iy = fminf(a.w, b.w) - fmaxf(a.y, b.y);
      float inter = ix * iy;
      float uni = (aarea + colA[j]) - inter;
      bool hit = (ix > 0.f) & (iy > 0.f) & ((double)inter >= M_TIE * (double)uni);
      word |= hit ? (1ull << j) : 0ull;
    }
    if (gi == gj)                          // strictly upper triangle j > i
      word &= (lane == 63) ? 0ull : (~0ull << (lane + 1));
  }
  // wave-aggregated emission: prefix-scan edge counts, ONE atomic per wave
  int nb = __popcll(word);
  int pfx = nb;
  for (int d = 1; d < 64; d <<= 1){
    int v = __shfl_up(pfx, d);
    if (lane >= d) pfx += v;
  }
  int total = __shfl(pfx, 63);
  if (total > 0){
    unsigned base = 0;
    if (lane == 0) base = atomicAdd(&ecnt[task*32 + gi], (unsigned)total);
    base = __shfl(base, 0);
    unsigned idx = base + (unsigned)(pfx - nb);
    unsigned* ep = eseg + (size_t)(task*32 + gi)*ESEG;
    while (word){
      int j = __ffsll(word) - 1; word &= word - 1;
      if (idx < ESEG) ep[idx] = ((unsigned)i << 16) | (unsigned)(gj*64 + j);
      ++idx;
    }
  }
}

// ---------------- K5: greedy-NMS fixpoint on LDS edges + ordered compaction ----------------
extern "C" __global__ void __launch_bounds__(256)
k_scan(const unsigned long long* __restrict__ cand, const unsigned* __restrict__ ecnt,
       const unsigned* __restrict__ eseg, unsigned long long* __restrict__ clist,
       unsigned* __restrict__ ccnt){
  __shared__ unsigned long long keepW[32], suppW[32], initW[32];
  __shared__ unsigned soff[33], wpfx[33];
  __shared__ unsigned ledge[6144];   // 24 KB edge cache
  __shared__ int s_changed;
  int task = blockIdx.x, img = task / 5, lvl = task % 5;
  int k = c_KSEL[lvl], nW = c_GLVL[lvl], tid = threadIdx.x;

  if (tid == 0){
    unsigned s = 0;
    for (int w = 0; w < nW; ++w){ soff[w] = s; s += min(ecnt[task*32 + w], (unsigned)ESEG); }
    soff[nW] = s;
  }
  if (tid < 32){
    unsigned long long v = 0ull;
    if (tid < nW){
      int rem = k - tid*64;
      v = (rem >= 64) ? ~0ull : ((1ull << rem) - 1ull);
    }
    initW[tid] = v; keepW[tid] = v;
  }
  __syncthreads();
  for (int w = 0; w < nW; ++w){
    unsigned c = soff[w+1] - soff[w];
    const unsigned* ep = eseg + (size_t)(task*32 + w)*ESEG;
    for (unsigned e = tid; e < c; e += 256){
      unsigned p = soff[w] + e;
      if (p < 6144u) ledge[p] = ep[e];
    }
  }
  __syncthreads();
  // greedy NMS == unique kernel of the suppression DAG (edges i<j only);
  // Jacobi iteration to fixpoint, deterministic OR-reduction.
  for (int iter = 0; iter < 4096; ++iter){
    if (tid < 32) suppW[tid] = 0ull;
    if (tid == 0) s_changed = 0;
    __syncthreads();
    for (int w = 0; w < nW; ++w){
      unsigned c = soff[w+1] - soff[w];
      const unsigned* ep = eseg + (size_t)(task*32 + w)*ESEG;
      for (unsigned e = tid; e < c; e += 256){
        unsigned p = soff[w] + e;
        unsigned ed = (p < 6144u) ? ledge[p] : ep[e];
        int i = (int)(ed >> 16), j = (int)(ed & 0xFFFFu);
        if ((keepW[i >> 6] >> (i & 63)) & 1ull)
          atomicOr(&suppW[j >> 6], 1ull << (j & 63));
      }
    }
    __syncthreads();
    if (tid < 32){
      unsigned long long nk = initW[tid] & ~suppW[tid];
      if (nk != keepW[tid]){ keepW[tid] = nk; s_changed = 1; }
    }
    __syncthreads();
    if (!s_changed) break;
  }
  if (tid == 0){
    unsigned s = 0;
    for (int w = 0; w < nW; ++w){ wpfx[w] = s; s += (unsigned)__popcll(keepW[w]); }
    ccnt[task] = s;
  }
  __syncthreads();
  size_t base = (size_t)img*KTOT + c_CBASE[lvl];
  for (int i = tid; i < k; i += 256){
    unsigned long long w = keepW[i >> 6];
    if ((w >> (i & 63)) & 1ull){
      unsigned long long lowmask = (i & 63) ? ((1ull << (i & 63)) - 1ull) : 0ull;
      unsigned rank = wpfx[i >> 6] + (unsigned)__popcll(w & lowmask);
      clist[base + rank] = cand[base + i];
    }
  }
}

// ---------------- K6: 5-way rank merge (no sort), 2 blocks/image ----------------
__device__ __forceinline__ int cntGreater(const unsigned long long* base, int len,
                                          unsigned long long x){
  int lo = 0, hi = len;          // descending array, unique keys
  while (lo < hi){
    int mid = (lo + hi) >> 1;
    if (base[mid] > x) lo = mid + 1; else hi = mid;
  }
  return lo;
}

extern "C" __global__ void __launch_bounds__(1024)
k_merge(const float* __restrict__ prop, const float* __restrict__ obj,
        const unsigned long long* __restrict__ clist, const unsigned* __restrict__ ccnt,
        float* __restrict__ out){
  __shared__ unsigned long long keys[KTOT];   // ~54.4 KB
  __shared__ int loff[6], lcnt[5];
  int img = blockIdx.x >> 1, half = blockIdx.x & 1, tid = threadIdx.x;
  if (tid == 0){
    int s = 0;
    for (int l = 0; l < 5; ++l){ lcnt[l] = (int)ccnt[img*5 + l]; loff[l] = s; s += lcnt[l]; }
    loff[5] = s;
  }
  __syncthreads();
  for (int l = 0; l < 5; ++l){
    size_t gb = (size_t)img*KTOT + c_CBASE[l];
    int c = lcnt[l], lo = loff[l];
    for (int e = tid; e < c; e += 1024) keys[lo + e] = clist[gb + e];
  }
  __syncthreads();
  const float4* pr = (const float4*)(prop + (size_t)img*ATOT*4);
  const float*  o  = obj + (size_t)img*ATOT;
  float* ob = out + (size_t)img*POST*4;
  float* os = out + (size_t)NIMG*POST*4 + (size_t)img*POST;
  int tot = loff[5];
  for (int tt = tid; ; tt += 1024){
    int t = 2*tt + half;
    if (t >= tot) break;
    int lvl = 0;
    while (t >= loff[lvl + 1]) ++lvl;
    unsigned long long x = keys[t];
    int pos = t - loff[lvl];
    for (int l = 0; l < 5; ++l){
      if (l == lvl) continue;
      pos += cntGreater(keys + loff[l], lcnt[l], x);
    }
    if (pos < POST){
      unsigned gidx = 0xFFFFFFFFu - (unsigned)(x & 0xFFFFFFFFull);
      float4 p = pr[gidx];
      ob[pos*4 + 0] = fminf(fmaxf(p.x, 0.f), 512.f);
      ob[pos*4 + 1] = fminf(fmaxf(p.y, 0.f), 512.f);
      ob[pos*4 + 2] = fminf(fmaxf(p.z, 0.f), 512.f);
      ob[pos*4 + 3] = fminf(fmaxf(p.w, 0.f), 512.f);
      double sgm = 1.0 / (1.0 + exp(-(double)o[gidx]));  // correctly-rounded f32 sigmoid
      os[pos] = (float)sgm;
    }
  }
}

// ---------------- launch ----------------
extern "C" void kernel_launch(void* const* d_in, const int* in_sizes, int n_in,
                              void* d_out, int out_size, void* d_ws, size_t ws_size,
                              hipStream_t stream){
  const float* prop = (const float*)d_in[0];
  const float* obj  = (const float*)d_in[1];
  char* ws = (char*)d_ws;
  // ws layout (bytes):
  unsigned*           cntA = (unsigned*)(ws);                        // 160        -> 160
  unsigned*           ecnt = (unsigned*)(ws + 160);                  // 40*32*4    -> 5280
  unsigned*           ccnt = (unsigned*)(ws + 5280);                 // 160        -> 5440
  unsigned long long* buf  = (unsigned long long*)(ws + 5632);       // 40*4096*8  -> 1316352
  unsigned long long* cand = (unsigned long long*)(ws + 1316352);    // 8*6960*8   -> 1761792
  unsigned long long* clist= (unsigned long long*)(ws + 1761792);    // 445440     -> 2207232
  float4*             cbox = (float4*)(ws + 2207232);                // 8*6960*16  -> 3098112
  unsigned*           hist = (unsigned*)(ws + 3098112);              // 88*4096*4  -> 4539904
  unsigned*           eseg = (unsigned*)(ws + 4539904);              // 40*32*1024*4 -> 9782784
  unsigned*           zzone= cntA;                                   // cntA+ecnt contiguous (1320 words)

  int out_n4 = out_size / 4;   // 80000 floats = 20000 float4
  hipLaunchKernelGGL(k_hist,   dim3(89),  dim3(256),  0, stream, obj, hist, zzone);
  hipLaunchKernelGGL(k_append, dim3(104), dim3(256),  0, stream, obj, hist, cntA, buf);
  hipLaunchKernelGGL(k_sort,   dim3(40),  dim3(1024), 0, stream, prop, cntA, buf, cand, cbox);
  hipLaunchKernelGGL(k_mask,   dim3(NTILES), dim3(64), 0, stream, cbox, ecnt, eseg,
                     (float4*)d_out, out_n4);
  hipLaunchKernelGGL(k_scan,   dim3(40),  dim3(256),  0, stream, cand, ecnt, eseg, clist, ccnt);
  hipLaunchKernelGGL(k_merge,  dim3(16),  dim3(1024), 0, stream, prop, obj, clist, ccnt, (float*)d_out);
}

// Round 7
// 224.850 us; speedup vs baseline: 2.4747x; 1.0868x over previous
//
#include <hip/hip_runtime.h>
#include <math.h>

// ---------------- problem constants (static shapes) ----------------
#define NIMG 8
#define ATOT 65472
#define KTOT 6960          // 2000+2000+2000+768+192
#define POST 2000
#define TILES_PER_IMG 1668 // 528*3 + 78 + 6
#define NTILES (NIMG*TILES_PER_IMG)
#define ESEG 1024          // edges per (task,gi) segment cap
// Exact tie boundary: f32_div(inter,uni) > 0.7f  <=>  inter/uni >= M_TIE.
// M_TIE = midpoint(0.7f, nextafterf(0.7f)); 25-bit mantissa; ties-to-even sends
// the midpoint UP. (double)inter >= M_TIE*(double)uni is exact: 25b+24b <= 53b.
// Validated bit-exact vs division predicate in rounds 4/5 (absmax 0.0).
#define M_TIE 0.7000000178813934326171875

__constant__ int c_NAPL[5]  = {49152,12288,3072,768,192};
__constant__ int c_LOFF[5]  = {0,49152,61440,64512,65280};
__constant__ int c_KSEL[5]  = {2000,2000,2000,768,192};
__constant__ int c_CBASE[5] = {0,2000,4000,6000,6768};
__constant__ int c_GLVL[5]  = {32,32,32,12,3};      // ceil(k/64)
__constant__ int c_TILEPFX[6] = {0,528,1056,1584,1662,1668};
// slice tables: 13 append-slots per image (first 11 are also hist-slots, lvl<3)
__constant__ int c_SLVL[13]  = {0,0,0,0,0,0,0,0,1,1,2,3,4};
__constant__ int c_SOFF13[13]= {0,6144,12288,18432,24576,30720,36864,43008,0,6144,0,0,0};
__constant__ int c_SLEN[13]  = {6144,6144,6144,6144,6144,6144,6144,6144,6144,6144,3072,768,192};
__constant__ int c_HS0[5] = {0,8,10,0,0};   // first hist-slot per lvl (lvl<3)
__constant__ int c_HSN[5] = {8,2,1,0,0};    // hist-slots per lvl

// monotone float->uint map (order-preserving for all finite floats)
__device__ __forceinline__ unsigned f2u(float f){
  unsigned b = __float_as_uint(f);
  return (b & 0x80000000u) ? ~b : (b | 0x80000000u);
}
// composite key: (value desc, global idx asc) when sorted descending
__device__ __forceinline__ unsigned long long mkkey(unsigned u, unsigned gidx){
  return ((unsigned long long)u << 32) | (unsigned long long)(0xFFFFFFFFu - gidx);
}

// in-LDS bitonic sort, descending, m = power of two (uniform per block)
__device__ void bitonic_desc(unsigned long long* sb, int m){
  int tid = threadIdx.x, nthr = blockDim.x;
  for (int size = 2; size <= m; size <<= 1){
    for (int stride = size >> 1; stride > 0; stride >>= 1){
      __syncthreads();
      for (int t = tid; t < (m >> 1); t += nthr){
        int lo = t & (stride - 1);
        int i  = ((t - lo) << 1) + lo;
        int j  = i + stride;
        bool desc = ((i & size) == 0);
        unsigned long long a = sb[i], b = sb[j];
        if (desc ? (a < b) : (a > b)) { sb[i] = b; sb[j] = a; }
      }
    }
  }
  __syncthreads();
}

// ---------------- K1: per-block LDS 12-bit histogram + counter zeroing ----------------
extern "C" __global__ void __launch_bounds__(256)
k_hist(const float* __restrict__ obj, unsigned* __restrict__ hist,
       unsigned* __restrict__ zzone){   // zzone = cntA(40) + ecnt(1280), contiguous
  __shared__ unsigned h[4096];
  int bid = blockIdx.x, tid = threadIdx.x;
  if (bid == 88){
    for (int i = tid; i < 1320; i += 256) zzone[i] = 0u;
    return;
  }
  int img = bid / 11, slot = bid % 11;
  int lvl = c_SLVL[slot], len4 = c_SLEN[slot] >> 2;
  for (int i = tid; i < 4096; i += 256) h[i] = 0u;
  __syncthreads();
  // slice offsets/lengths all divisible by 4 -> exact aligned float4 sweep
  const float4* o4 = (const float4*)(obj + (size_t)img*ATOT + c_LOFF[lvl] + c_SOFF13[slot]);
  for (int i = tid; i < len4; i += 256){
    float4 v = o4[i];
    atomicAdd(&h[f2u(v.x) >> 20], 1u);
    atomicAdd(&h[f2u(v.y) >> 20], 1u);
    atomicAdd(&h[f2u(v.z) >> 20], 1u);
    atomicAdd(&h[f2u(v.w) >> 20], 1u);
  }
  __syncthreads();
  unsigned* hout = hist + (size_t)bid*4096;
  for (int i = tid; i < 4096; i += 256) hout[i] = h[i];
}

// ---------------- K2: inline threshold + slice append, 1 global atomic per block ----------------
extern "C" __global__ void __launch_bounds__(256)
k_append(const float* __restrict__ obj, const unsigned* __restrict__ hist,
         unsigned* __restrict__ cntA, unsigned long long* __restrict__ buf){
  __shared__ unsigned hcomb[4096];          // 16 KB combined histogram
  __shared__ unsigned csum[256];
  __shared__ unsigned long long lbuf[2048]; // 16 KB append buffer
  __shared__ unsigned s_T, s_cnt, s_gbase;
  int bid = blockIdx.x, tid = threadIdx.x;
  int img = bid / 13, slot = bid % 13;
  int lvl = c_SLVL[slot], task = img*5 + lvl;
  int len4 = c_SLEN[slot] >> 2;

  if (lvl < 3){
    // rebuild this task's combined 4096-bin histogram; find k-th-largest's bin b12
    int hs0 = c_HS0[lvl], hsn = c_HSN[lvl];
    unsigned s = 0;
    for (int b = 0; b < 16; ++b){
      unsigned v = 0;
      for (int hs = 0; hs < hsn; ++hs)
        v += hist[(size_t)(img*11 + hs0 + hs)*4096 + tid*16 + b];
      hcomb[tid*16 + b] = v;
      s += v;
    }
    csum[tid] = s;
    __syncthreads();
    if (tid == 0){
      unsigned k = (unsigned)c_KSEL[lvl], cum = 0, bstar = 0;
      for (int c = 255; c >= 0; --c){
        if (cum + csum[c] >= k){
          for (int j = 15; j >= 0; --j){
            cum += hcomb[c*16 + j];
            if (cum >= k){ bstar = (unsigned)(c*16 + j); break; }
          }
          break;
        }
        cum += csum[c];
      }
      s_T = bstar;
    }
  } else if (tid == 0) s_T = 0u;
  if (tid == 0) s_cnt = 0u;
  __syncthreads();
  unsigned T = s_T;

  int abase = c_LOFF[lvl] + c_SOFF13[slot];
  const float4* o4 = (const float4*)(obj + (size_t)img*ATOT + abase);
  for (int i = tid; i < len4; i += 256){
    float4 v = o4[i];
    float vv[4] = {v.x, v.y, v.z, v.w};
    #pragma unroll
    for (int c = 0; c < 4; ++c){
      unsigned u = f2u(vv[c]);
      if ((u >> 20) >= T){
        unsigned p = atomicAdd(&s_cnt, 1u);   // LDS atomic
        if (p < 2048u) lbuf[p] = mkkey(u, (unsigned)(abase + i*4 + c));
      }
    }
  }
  __syncthreads();
  unsigned c = min(s_cnt, 2048u);
  if (tid == 0) s_gbase = atomicAdd(&cntA[task], c);  // one global atomic per block
  __syncthreads();
  unsigned gb = s_gbase;
  unsigned long long* bp = buf + (size_t)task*4096;
  for (unsigned i = tid; i < c; i += 256){
    unsigned p = gb + i;
    if (p < 4096u) bp[p] = lbuf[i];
  }
}

// ---------------- K3: per-task sort (<=4096) + emit sorted cand + clipped boxes ----------------
extern "C" __global__ void __launch_bounds__(1024)
k_sort(const float* __restrict__ prop, const unsigned* __restrict__ cntA,
       const unsigned long long* __restrict__ buf,
       unsigned long long* __restrict__ cand, float4* __restrict__ cbox){
  __shared__ unsigned long long sb[4096];   // 32 KB
  int task = blockIdx.x, img = task / 5, lvl = task % 5;
  int k = c_KSEL[lvl], tid = threadIdx.x;
  int cnt = (int)min(cntA[task], 4096u);    // superset of top-k by construction
  const unsigned long long* b = buf + (size_t)task*4096;
  for (int i = tid; i < cnt; i += 1024) sb[i] = b[i];
  int m = 256; while (m < k || m < cnt) m <<= 1;
  for (int i = cnt + tid; i < m; i += 1024) sb[i] = 0ull;
  bitonic_desc(sb, m);

  const float4* pr = (const float4*)(prop + (size_t)img*ATOT*4);
  for (int i = tid; i < k; i += 1024){
    unsigned long long key = sb[i];
    size_t slot = (size_t)img*KTOT + c_CBASE[lvl] + i;
    cand[slot] = key;
    unsigned gidx = 0xFFFFFFFFu - (unsigned)(key & 0xFFFFFFFFull);
    float4 p = pr[gidx];
    cbox[slot] = make_float4(fminf(fmaxf(p.x,0.f),512.f), fminf(fmaxf(p.y,0.f),512.f),
                             fminf(fmaxf(p.z,0.f),512.f), fminf(fmaxf(p.w,0.f),512.f));
  }
}

// ---------------- K4: branchless IoU tiles -> segmented edge lists; zero d_out ----------------
extern "C" __global__ void __launch_bounds__(64)
k_mask(const float4* __restrict__ cbox, unsigned* __restrict__ ecnt,
       unsigned* __restrict__ eseg, float4* __restrict__ out4, int out_n4){
  __shared__ float4 colb[64];
  __shared__ float  colA[64];
  int bid = blockIdx.x, lane = threadIdx.x;
  // fold d_out zero-fill into this (pre-merge) kernel: first 313 blocks
  if (bid < 313){
    int i = bid*64 + lane;
    if (i < out_n4) out4[i] = make_float4(0.f,0.f,0.f,0.f);
  }
  int img = bid / TILES_PER_IMG, r = bid % TILES_PER_IMG;
  int lvl = 0;
  while (r >= c_TILEPFX[lvl + 1]) ++lvl;
  int t = r - c_TILEPFX[lvl];
  int G = c_GLVL[lvl], k = c_KSEL[lvl];
  int gi = 0;
  while (t >= G - gi){ t -= G - gi; ++gi; }
  int gj = gi + t;
  int task = img*5 + lvl;
  const float4* cb = cbox + (size_t)img*KTOT + c_CBASE[lvl];

  int jj = gj*64 + lane;
  float4 bb = (jj < k) ? cb[jj] : make_float4(0.f,0.f,0.f,0.f);  // zero box never hits
  colb[lane] = bb;
  colA[lane] = (bb.z - bb.x) * (bb.w - bb.y);
  __syncthreads();

  int i = gi*64 + lane;
  unsigned long long word = 0ull;
  if (i < k){
    float4 a = cb[i];
    float aarea = (a.z - a.x) * (a.w - a.y);
    for (int j = 0; j < 64; ++j){
      float4 b = colb[j];                  // wave-uniform address: LDS broadcast
      float ix = fminf(a.z, b.z) - fmaxf(a.x, b.x);
      float iy = fminf(a.w, b.w) - fmaxf(a.y, b.y);
      float inter = ix * iy;
      float uni = (aarea + colA[j]) - inter;
      bool hit = (ix > 0.f) & (iy > 0.f) & ((double)inter >= M_TIE * (double)uni);
      word |= hit ? (1ull << j) : 0ull;
    }
    if (gi == gj)                          // strictly upper triangle j > i
      word &= (lane == 63) ? 0ull : (~0ull << (lane + 1));
  }
  // wave-aggregated emission: prefix-scan edge counts, ONE atomic per wave
  int nb = __popcll(word);
  int pfx = nb;
  for (int d = 1; d < 64; d <<= 1){
    int v = __shfl_up(pfx, d);
    if (lane >= d) pfx += v;
  }
  int total = __shfl(pfx, 63);
  if (total > 0){
    unsigned base = 0;
    if (lane == 0) base = atomicAdd(&ecnt[task*32 + gi], (unsigned)total);
    base = __shfl(base, 0);
    unsigned idx = base + (unsigned)(pfx - nb);
    unsigned* ep = eseg + (size_t)(task*32 + gi)*ESEG;
    while (word){
      int j = __ffsll(word) - 1; word &= word - 1;
      if (idx < ESEG) ep[idx] = ((unsigned)i << 16) | (unsigned)(gj*64 + j);
      ++idx;
    }
  }
}

// ---------------- K5: exact sequential greedy NMS as a single word-sweep ----------------
// ONE WAVE per task: every LDS interaction (sm build, serial resolve, cross-word
// OR) happens within a single 64-lane wave => no cross-wave interleaving is
// possible; __syncthreads() on a 1-wave block is ~free and provides LDS
// ordering. Word w's keep bits are FINAL before its suppressions propagate =>
// identical output to sequential greedy NMS. O(E), each edge touched twice.
extern "C" __global__ void __launch_bounds__(64)
k_scan(const unsigned long long* __restrict__ cand, const unsigned* __restrict__ ecnt,
       const unsigned* __restrict__ eseg, unsigned long long* __restrict__ clist,
       unsigned* __restrict__ ccnt){
  __shared__ unsigned ledge[6144];          // 24 KB edge cache
  __shared__ unsigned soff[33], wpfx[33];
  __shared__ unsigned long long sm[64];     // intra-word suppression rows
  __shared__ unsigned long long remW[32], keepW[32];
  __shared__ unsigned long long s_hasI;
  int task = blockIdx.x, img = task / 5, lvl = task % 5;
  int k = c_KSEL[lvl], nW = c_GLVL[lvl], tid = threadIdx.x;

  if (tid == 0){
    unsigned s = 0;
    for (int w = 0; w < nW; ++w){ soff[w] = s; s += min(ecnt[task*32 + w], (unsigned)ESEG); }
    soff[nW] = s;
  }
  if (tid < 32) remW[tid] = 0ull;
  __syncthreads();
  // stage all edges into LDS (global fallback for overflow beyond 6144)
  for (int w = 0; w < nW; ++w){
    unsigned c = soff[w+1] - soff[w];
    const unsigned* ep = eseg + (size_t)(task*32 + w)*ESEG;
    for (unsigned e = tid; e < c; e += 64){
      unsigned p = soff[w] + e;
      if (p < 6144u) ledge[p] = ep[e];
    }
  }
  __syncthreads();

  for (int w = 0; w < nW; ++w){
    unsigned c = soff[w+1] - soff[w];      // wave-uniform (LDS), barrier-safe skip
    if (c == 0) continue;
    const unsigned* ep = eseg + (size_t)(task*32 + w)*ESEG;
    // phase 1: build intra-word suppression matrix from segment w
    sm[tid] = 0ull;
    if (tid == 0) s_hasI = 0ull;
    __syncthreads();
    for (unsigned e = tid; e < c; e += 64){
      unsigned p = soff[w] + e;
      unsigned ed = (p < 6144u) ? ledge[p] : ep[e];
      int i = (int)(ed >> 16), j = (int)(ed & 0xFFFFu);
      if ((j >> 6) == w){
        atomicOr(&sm[i & 63], 1ull << (j & 63));
        atomicOr(&s_hasI, 1ull << (i & 63));
      }
    }
    __syncthreads();
    // phase 2: serial greedy resolve within word w (ascending i = global order;
    // all suppressors from earlier words already final in remW[w])
    if (tid == 0){
      unsigned long long r = remW[w];
      unsigned long long x = s_hasI & ~r;
      while (x){
        int i = __ffsll(x) - 1;
        r |= sm[i];                          // i kept -> suppress its intra targets
        x &= ~(1ull << i);
        x &= ~r;
      }
      remW[w] = r;
    }
    __syncthreads();
    // phase 3: apply cross-word suppression from KEPT rows of word w
    unsigned long long keep_w = ~remW[w];    // edges only exist for i<k
    for (unsigned e = tid; e < c; e += 64){
      unsigned p = soff[w] + e;
      unsigned ed = (p < 6144u) ? ledge[p] : ep[e];
      int i = (int)(ed >> 16), j = (int)(ed & 0xFFFFu), wj = j >> 6;
      if (wj != w && ((keep_w >> (i & 63)) & 1ull))
        atomicOr(&remW[wj], 1ull << (j & 63));
    }
    __syncthreads();
  }

  // compact kept candidates (preserves sorted order within level)
  if (tid < 32){
    unsigned long long v = 0ull;
    if (tid < nW){
      int rem = k - tid*64;
      v = (rem >= 64) ? ~0ull : ((1ull << rem) - 1ull);
    }
    keepW[tid] = v & ~remW[tid];
  }
  __syncthreads();
  if (tid == 0){
    unsigned s = 0;
    for (int w = 0; w < nW; ++w){ wpfx[w] = s; s += (unsigned)__popcll(keepW[w]); }
    ccnt[task] = s;
  }
  __syncthreads();
  size_t base = (size_t)img*KTOT + c_CBASE[lvl];
  for (int i = tid; i < k; i += 64){
    unsigned long long w = keepW[i >> 6];
    if ((w >> (i & 63)) & 1ull){
      unsigned long long lowmask = (i & 63) ? ((1ull << (i & 63)) - 1ull) : 0ull;
      unsigned rank = wpfx[i >> 6] + (unsigned)__popcll(w & lowmask);
      clist[base + rank] = cand[base + i];
    }
  }
}

// ---------------- K6: 5-way rank merge (no sort), 2 blocks/image ----------------
__device__ __forceinline__ int cntGreater(const unsigned long long* base, int len,
                                          unsigned long long x){
  int lo = 0, hi = len;          // descending array, unique keys
  while (lo < hi){
    int mid = (lo + hi) >> 1;
    if (base[mid] > x) lo = mid + 1; else hi = mid;
  }
  return lo;
}

extern "C" __global__ void __launch_bounds__(1024)
k_merge(const float* __restrict__ prop, const float* __restrict__ obj,
        const unsigned long long* __restrict__ clist, const unsigned* __restrict__ ccnt,
        float* __restrict__ out){
  __shared__ unsigned long long keys[KTOT];   // ~54.4 KB
  __shared__ int loff[6], lcnt[5];
  int img = blockIdx.x >> 1, half = blockIdx.x & 1, tid = threadIdx.x;
  if (tid == 0){
    int s = 0;
    for (int l = 0; l < 5; ++l){ lcnt[l] = (int)ccnt[img*5 + l]; loff[l] = s; s += lcnt[l]; }
    loff[5] = s;
  }
  __syncthreads();
  for (int l = 0; l < 5; ++l){
    size_t gb = (size_t)img*KTOT + c_CBASE[l];
    int c = lcnt[l], lo = loff[l];
    for (int e = tid; e < c; e += 1024) keys[lo + e] = clist[gb + e];
  }
  __syncthreads();
  const float4* pr = (const float4*)(prop + (size_t)img*ATOT*4);
  const float*  o  = obj + (size_t)img*ATOT;
  float* ob = out + (size_t)img*POST*4;
  float* os = out + (size_t)NIMG*POST*4 + (size_t)img*POST;
  int tot = loff[5];
  for (int tt = tid; ; tt += 1024){
    int t = 2*tt + half;
    if (t >= tot) break;
    int lvl = 0;
    while (t >= loff[lvl + 1]) ++lvl;
    unsigned long long x = keys[t];
    int pos = t - loff[lvl];
    for (int l = 0; l < 5; ++l){
      if (l == lvl) continue;
      pos += cntGreater(keys + loff[l], lcnt[l], x);
    }
    if (pos < POST){
      unsigned gidx = 0xFFFFFFFFu - (unsigned)(x & 0xFFFFFFFFull);
      float4 p = pr[gidx];
      ob[pos*4 + 0] = fminf(fmaxf(p.x, 0.f), 512.f);
      ob[pos*4 + 1] = fminf(fmaxf(p.y, 0.f), 512.f);
      ob[pos*4 + 2] = fminf(fmaxf(p.z, 0.f), 512.f);
      ob[pos*4 + 3] = fminf(fmaxf(p.w, 0.f), 512.f);
      double sgm = 1.0 / (1.0 + exp(-(double)o[gidx]));  // correctly-rounded f32 sigmoid
      os[pos] = (float)sgm;
    }
  }
}

// ---------------- launch ----------------
extern "C" void kernel_launch(void* const* d_in, const int* in_sizes, int n_in,
                              void* d_out, int out_size, void* d_ws, size_t ws_size,
                              hipStream_t stream){
  const float* prop = (const float*)d_in[0];
  const float* obj  = (const float*)d_in[1];
  char* ws = (char*)d_ws;
  // ws layout (bytes):
  unsigned*           cntA = (unsigned*)(ws);                        // 160        -> 160
  unsigned*           ecnt = (unsigned*)(ws + 160);                  // 40*32*4    -> 5280
  unsigned*           ccnt = (unsigned*)(ws + 5280);                 // 160        -> 5440
  unsigned long long* buf  = (unsigned long long*)(ws + 5632);       // 40*4096*8  -> 1316352
  unsigned long long* cand = (unsigned long long*)(ws + 1316352);    // 8*6960*8   -> 1761792
  unsigned long long* clist= (unsigned long long*)(ws + 1761792);    // 445440     -> 2207232
  float4*             cbox = (float4*)(ws + 2207232);                // 8*6960*16  -> 3098112
  unsigned*           hist = (unsigned*)(ws + 3098112);              // 88*4096*4  -> 4539904
  unsigned*           eseg = (unsigned*)(ws + 4539904);              // 40*32*1024*4 -> 9782784
  unsigned*           zzone= cntA;                                   // cntA+ecnt contiguous (1320 words)

  int out_n4 = out_size / 4;   // 80000 floats = 20000 float4
  hipLaunchKernelGGL(k_hist,   dim3(89),  dim3(256),  0, stream, obj, hist, zzone);
  hipLaunchKernelGGL(k_append, dim3(104), dim3(256),  0, stream, obj, hist, cntA, buf);
  hipLaunchKernelGGL(k_sort,   dim3(40),  dim3(1024), 0, stream, prop, cntA, buf, cand, cbox);
  hipLaunchKernelGGL(k_mask,   dim3(NTILES), dim3(64), 0, stream, cbox, ecnt, eseg,
                     (float4*)d_out, out_n4);
  hipLaunchKernelGGL(k_scan,   dim3(40),  dim3(64),   0, stream, cand, ecnt, eseg, clist, ccnt);
  hipLaunchKernelGGL(k_merge,  dim3(16),  dim3(1024), 0, stream, prop, obj, clist, ccnt, (float*)d_out);
}